// Round 14
// baseline (104.718 us; speedup 1.0000x reference)
//
#include <hip/hip_runtime.h>
#include <math.h>

typedef _Float16 f16x8  __attribute__((ext_vector_type(8)));    // MFMA A/B operand (4 VGPRs)
typedef _Float16 h2v    __attribute__((ext_vector_type(2)));
typedef float    f32x16 __attribute__((ext_vector_type(16)));   // MFMA C/D operand (32x32)
typedef float    f32x4  __attribute__((ext_vector_type(4)));
typedef __fp16   h2a    __attribute__((ext_vector_type(2)));    // cvt_pkrtz result
typedef unsigned u32x4  __attribute__((ext_vector_type(4)));

#define WS     10
#define HID    32
#define BDIM   256
#define NWAVE  4
#define GN     32                 // points per group = MFMA N
#define T_LEN  4096
#define GPR    (T_LEN / GN)       // 128 groups per row
#define NGTOT  (GPR * 1024)       // 131072 groups total
#define GRID   1280               // 5 blocks/CU exactly -> one residency round
#define WSTRIDE (GRID * NWAVE)    // 5120 waves: 25-26 groups per wave

__device__ inline unsigned pack2u(float a, float b) {
    h2a t = __builtin_amdgcn_cvt_pkrtz(a, b);   // a -> low16, b -> high16
    return __builtin_bit_cast(unsigned, t);
}
__device__ inline unsigned relu2(unsigned u) {  // v_pk_max_f16 with 0
    h2v x = __builtin_bit_cast(h2v, u);
    h2v z = {(_Float16)0.0f, (_Float16)0.0f};
    return __builtin_bit_cast(unsigned, __builtin_elementwise_max(x, z));
}

// (256,5): reg cap ~102/lane -> 5 waves/SIMD (20/CU). One LIGHT chain per
// wave; cross-wave overlap needs no compiler cooperation (r9-r13 lesson:
// in-wave ILP gets serialized by the allocator; AGPR-resident accumulators
// made the unified-file total ~135 and silently capped occupancy at ~3-4).
__global__ __launch_bounds__(BDIM, 5)
void hurst_wave5(const float* __restrict__ returns,
                 const float* __restrict__ W1, const float* __restrict__ b1,
                 const float* __restrict__ W2, const float* __restrict__ b2,
                 const float* __restrict__ W3, const float* __restrict__ b3,
                 float* __restrict__ out)
{
    const int tid  = threadIdx.x;
    const int wid  = tid >> 6;
    const int lane = tid & 63;
    const int n    = lane & 31;    // MFMA m (A-row) / n (B/C col)
    const int hi   = lane >> 5;    // k-half (A/B) / row-half (C/D)

    // ---- bias C-operands in C-layout: row(r)=(r&3)+8(r>>2)+4hi ----
    f32x16 b1v, b2v;
    #pragma unroll
    for (int i = 0; i < 4; ++i) {
        const f32x4 v1 = ((const f32x4*)b1)[2 * i + hi];
        const f32x4 v2 = ((const f32x4*)b2)[2 * i + hi];
        #pragma unroll
        for (int o = 0; o < 4; ++o) {
            b1v[4 * i + o] = v1[o];
            b2v[4 * i + o] = v2[o];
        }
    }
    const float corr = b3[0] - b2[4 * hi];   // undoes b2v[0] riding L3's C-init

    // ---- A-frags; phi(k)=swap(bit2,bit3) absorbs the C->B layout permutation
    // between stages (verified r6-r13, absmax 1.95e-3) ----
    f16x8 a1, a2lo, a2hi, a3lo, a3hi;
    #pragma unroll
    for (int jj = 0; jj < 8; ++jj) {
        const int k  = 8 * hi + jj;
        a1[jj] = (k < WS) ? (_Float16)W1[k * HID + n] : (_Float16)0.0f;   // W1^T, K 10->16 pad
        const int kf = (k & 3) | ((k & 4) << 1) | ((k & 8) >> 1);         // phi: swap bits 2<->3
        a2lo[jj] = (_Float16)W2[kf * HID + n];
        a2hi[jj] = (_Float16)W2[(16 + kf) * HID + n];
        a3lo[jj] = (_Float16)W3[kf];          // broadcast over m
        a3hi[jj] = (_Float16)W3[16 + kf];
    }

    // ---- flat grid-stride over all groups; row index is wave-uniform ----
    const int g0 = blockIdx.x * NWAVE + wid;

    for (int g = g0; g < NGTOT; g += WSTRIDE) {
        const int   row  = g >> 7;            // wave-uniform (SGPR math)
        const int   tg   = (g & 127) * GN + n;
        const int   ws   = (tg >= WS) ? (tg - WS) : 0;   // head points reuse window 0
        const float* rp  = returns + (size_t)row * T_LEN;

        // ---- 2x 16B loads, both in-bounds: A @ ws+6*hi gives (e0..e3 | e6..e9),
        // B @ ws+4 gives (e4..e7 | discard). max addr = tg-1 <= 4094. ----
        float A[4], Bv[4];
        __builtin_memcpy(A,  rp + ws + 6 * hi, 16);
        __builtin_memcpy(Bv, rp + ws + 4,      16);

        // ---- X B-frag: k=8*hi+jj; hi=1 half is (e8,e9,0,0,...,0) ----
        u32x4 xu;
        xu[0] = hi ? pack2u(A[2], A[3]) : pack2u(A[0], A[1]);   // (e8,e9) | (e0,e1)
        xu[1] = hi ? 0u : pack2u(A[2], A[3]);                   //  zeros  | (e2,e3)
        xu[2] = hi ? 0u : pack2u(Bv[0], Bv[1]);                 //  zeros  | (e4,e5)
        xu[3] = hi ? 0u : pack2u(Bv[2], Bv[3]);                 //  zeros  | (e6,e7)
        const f16x8 xb = __builtin_bit_cast(f16x8, xu);

        // ---- L1 (bias rides C) ----
        f32x16 d1 = __builtin_amdgcn_mfma_f32_32x32x16_f16(a1, xb, b1v, 0, 0, 0);

        u32x4 p1lo, p1hi;
        #pragma unroll
        for (int q = 0; q < 4; ++q) {
            p1lo[q] = relu2(pack2u(d1[2 * q],     d1[2 * q + 1]));
            p1hi[q] = relu2(pack2u(d1[8 + 2 * q], d1[9 + 2 * q]));
        }

        // ---- L2 (bias rides C) ----
        f32x16 d2 = __builtin_amdgcn_mfma_f32_32x32x16_f16(
                        a2lo, __builtin_bit_cast(f16x8, p1lo), b2v, 0, 0, 0);
        d2 = __builtin_amdgcn_mfma_f32_32x32x16_f16(
                        a2hi, __builtin_bit_cast(f16x8, p1hi), d2, 0, 0, 0);

        u32x4 p2lo, p2hi;
        #pragma unroll
        for (int q = 0; q < 4; ++q) {
            p2lo[q] = relu2(pack2u(d2[2 * q],     d2[2 * q + 1]));
            p2hi[q] = relu2(pack2u(d2[8 + 2 * q], d2[9 + 2 * q]));
        }

        // ---- L3: A = W3 broadcast over rows; C-init reuses resident b2v ----
        f32x16 d3 = __builtin_amdgcn_mfma_f32_32x32x16_f16(
                        a3lo, __builtin_bit_cast(f16x8, p2lo), b2v, 0, 0, 0);
        d3 = __builtin_amdgcn_mfma_f32_32x32x16_f16(
                        a3hi, __builtin_bit_cast(f16x8, p2hi), d3, 0, 0, 0);

        // ---- sigmoid epilogue; 32 coalesced stores from half 0 ----
        const float o = 0.5f * __builtin_amdgcn_rcpf(1.0f + __expf(-(d3[0] + corr)));
        if (hi == 0)
            out[(size_t)row * T_LEN + tg] = o;
    }
}

extern "C" void kernel_launch(void* const* d_in, const int* in_sizes, int n_in,
                              void* d_out, int out_size, void* d_ws, size_t ws_size,
                              hipStream_t stream) {
    const float* returns = (const float*)d_in[0];
    const float* W1      = (const float*)d_in[1];
    const float* b1      = (const float*)d_in[2];
    const float* W2      = (const float*)d_in[3];
    const float* b2      = (const float*)d_in[4];
    const float* W3      = (const float*)d_in[5];
    const float* b3      = (const float*)d_in[6];
    float* out = (float*)d_out;

    dim3 grid(GRID, 1, 1);    // 1280 blocks = 5 blocks/CU, one residency round
    dim3 block(BDIM, 1, 1);
    hurst_wave5<<<grid, block, 0, stream>>>(returns, W1, b1, W2, b2, W3, b3, out);
}

// Round 15
// 99.554 us; speedup vs baseline: 1.0519x; 1.0519x over previous
//
#include <hip/hip_runtime.h>
#include <math.h>

typedef _Float16 f16x8  __attribute__((ext_vector_type(8)));    // MFMA A/B operand (4 VGPRs)
typedef _Float16 h2v    __attribute__((ext_vector_type(2)));
typedef float    f32x16 __attribute__((ext_vector_type(16)));   // MFMA C/D operand (32x32)
typedef float    f32x4  __attribute__((ext_vector_type(4)));
typedef __fp16   h2a    __attribute__((ext_vector_type(2)));    // cvt_pkrtz result
typedef unsigned u32x4  __attribute__((ext_vector_type(4)));

#define WS    10
#define HID   32
#define BDIM  256
#define NWAVE 4
#define GN    32                  // points per group = MFMA N
#define T_LEN 4096
#define NGRP  (T_LEN / GN)        // 128 groups per row; 32 per wave
#define PADN  4104                // padded f16 elements per LDS row copy

__device__ inline unsigned pack2u(float a, float b) {
    h2a t = __builtin_amdgcn_cvt_pkrtz(a, b);   // a -> low16, b -> high16
    return __builtin_bit_cast(unsigned, t);
}
__device__ inline unsigned relu2(unsigned u) {  // v_pk_max_f16 with 0
    h2v x = __builtin_bit_cast(h2v, u);
    h2v z = {(_Float16)0.0f, (_Float16)0.0f};
    return __builtin_bit_cast(unsigned, __builtin_elementwise_max(x, z));
}

// One block per row. Row cached in LDS as packed f16 TWICE: buf0 pairs
// (e2j,e2j+1), buf1 pairs (e2j+1,e2j+2). ws parity picks the copy, making
// each lane's X-frag one dword-aligned 16B LDS read: the group loop has
// ZERO global loads / cvt for X (r9-r14: per-group VMEM latency headed the
// chain and ~8 lanes redundantly re-converted every element every group).
__global__ __launch_bounds__(BDIM, 4)
void hurst_ldsrow(const float* __restrict__ returns,
                  const float* __restrict__ W1, const float* __restrict__ b1,
                  const float* __restrict__ W2, const float* __restrict__ b2,
                  const float* __restrict__ W3, const float* __restrict__ b3,
                  float* __restrict__ out)
{
    __shared__ __align__(16) _Float16 sbuf[2 * PADN];   // 16416 B

    const int tid  = threadIdx.x;
    const int wid  = tid >> 6;
    const int lane = tid & 63;
    const int n    = lane & 31;    // MFMA m (A-row) / n (B/C col)
    const int hi   = lane >> 5;    // k-half (A/B) / row-half (C/D)

    // ---- bias C-operands in C-layout: row(r)=(r&3)+8(r>>2)+4hi ----
    f32x16 b1v, b2v;
    #pragma unroll
    for (int i = 0; i < 4; ++i) {
        const f32x4 v1 = ((const f32x4*)b1)[2 * i + hi];
        const f32x4 v2 = ((const f32x4*)b2)[2 * i + hi];
        #pragma unroll
        for (int o = 0; o < 4; ++o) {
            b1v[4 * i + o] = v1[o];
            b2v[4 * i + o] = v2[o];
        }
    }
    const float corr = b3[0] - b2[4 * hi];   // undoes b2v[0] riding L3's C-init

    // ---- A-frags; phi(k)=swap(bit2,bit3) absorbs the C->B layout permutation
    // between stages (verified r6-r14, absmax 1.95e-3) ----
    f16x8 a1, a2lo, a2hi, a3lo, a3hi;
    #pragma unroll
    for (int jj = 0; jj < 8; ++jj) {
        const int k  = 8 * hi + jj;
        a1[jj] = (k < WS) ? (_Float16)W1[k * HID + n] : (_Float16)0.0f;   // W1^T, K 10->16 pad
        const int kf = (k & 3) | ((k & 4) << 1) | ((k & 8) >> 1);         // phi: swap bits 2<->3
        a2lo[jj] = (_Float16)W2[kf * HID + n];
        a2hi[jj] = (_Float16)W2[(16 + kf) * HID + n];
        a3lo[jj] = (_Float16)W3[kf];          // broadcast over m
        a3hi[jj] = (_Float16)W3[16 + kf];
    }

    const float* rp   = returns + (size_t)blockIdx.x * T_LEN;
    float*       optr = out     + (size_t)blockIdx.x * T_LEN;

    // ---- build the two packed-f16 row copies (16 elements per thread) ----
    {
        float f[17];
        __builtin_memcpy(f, rp + 16 * tid, 64);            // 16 coalesced floats
        const int nx = 16 * tid + 16;
        f[16] = rp[(nx < T_LEN) ? nx : (T_LEN - 1)];       // clamped edge (unused pair)

        u32x4 q0a, q0b, q1a, q1b;
        #pragma unroll
        for (int k = 0; k < 4; ++k) {
            q0a[k] = pack2u(f[2 * k],     f[2 * k + 1]);
            q0b[k] = pack2u(f[8 + 2 * k], f[9 + 2 * k]);
            q1a[k] = pack2u(f[2 * k + 1], f[2 * k + 2]);
            q1b[k] = pack2u(f[9 + 2 * k], f[10 + 2 * k]);
        }
        unsigned* s32 = (unsigned*)sbuf;
        *(u32x4*)(s32 + 8 * tid)                  = q0a;   // buf0 dwords 8t..8t+3
        *(u32x4*)(s32 + 8 * tid + 4)              = q0b;
        *(u32x4*)(s32 + (PADN / 2) + 8 * tid)     = q1a;   // buf1 (PADN/2 = 2052 dwords)
        *(u32x4*)(s32 + (PADN / 2) + 8 * tid + 4) = q1b;
    }
    __syncthreads();

    for (int g = wid; g < NGRP; g += NWAVE) {
        const int tg = g * GN + n;
        const int ws = (tg >= WS) ? (tg - WS) : 0;   // head points reuse window 0 (ws=0: even)

        // ---- X frag: one 16B dword-aligned LDS read; parity picks the copy.
        // hi=0 reads pairs (e0,e1)..(e6,e7); hi=1 reads (e4,e5)..(e10,e11),
        // keeps (e8,e9), zero-pads k=10..15. ----
        const unsigned eoff = (ws & 1) ? (unsigned)(PADN + ws - 1) : (unsigned)ws;
        u32x4 q;
        __builtin_memcpy(&q, (const char*)sbuf + 2 * eoff + 8 * hi, 16);
        u32x4 xu;
        xu[0] = hi ? q[2] : q[0];
        xu[1] = hi ? 0u   : q[1];
        xu[2] = hi ? 0u   : q[2];
        xu[3] = hi ? 0u   : q[3];
        const f16x8 xb = __builtin_bit_cast(f16x8, xu);

        // ---- L1 (bias rides C) ----
        f32x16 d1 = __builtin_amdgcn_mfma_f32_32x32x16_f16(a1, xb, b1v, 0, 0, 0);

        u32x4 p1lo, p1hi;
        #pragma unroll
        for (int qq = 0; qq < 4; ++qq) {
            p1lo[qq] = relu2(pack2u(d1[2 * qq],     d1[2 * qq + 1]));
            p1hi[qq] = relu2(pack2u(d1[8 + 2 * qq], d1[9 + 2 * qq]));
        }

        // ---- L2 (bias rides C) ----
        f32x16 d2 = __builtin_amdgcn_mfma_f32_32x32x16_f16(
                        a2lo, __builtin_bit_cast(f16x8, p1lo), b2v, 0, 0, 0);
        d2 = __builtin_amdgcn_mfma_f32_32x32x16_f16(
                        a2hi, __builtin_bit_cast(f16x8, p1hi), d2, 0, 0, 0);

        u32x4 p2lo, p2hi;
        #pragma unroll
        for (int qq = 0; qq < 4; ++qq) {
            p2lo[qq] = relu2(pack2u(d2[2 * qq],     d2[2 * qq + 1]));
            p2hi[qq] = relu2(pack2u(d2[8 + 2 * qq], d2[9 + 2 * qq]));
        }

        // ---- L3: A = W3 broadcast over rows; C-init reuses resident b2v ----
        f32x16 d3 = __builtin_amdgcn_mfma_f32_32x32x16_f16(
                        a3lo, __builtin_bit_cast(f16x8, p2lo), b2v, 0, 0, 0);
        d3 = __builtin_amdgcn_mfma_f32_32x32x16_f16(
                        a3hi, __builtin_bit_cast(f16x8, p2hi), d3, 0, 0, 0);

        // ---- sigmoid epilogue; 32 coalesced stores from half 0 ----
        const float o = 0.5f * __builtin_amdgcn_rcpf(1.0f + __expf(-(d3[0] + corr)));
        if (hi == 0)
            optr[tg] = o;
    }
}

extern "C" void kernel_launch(void* const* d_in, const int* in_sizes, int n_in,
                              void* d_out, int out_size, void* d_ws, size_t ws_size,
                              hipStream_t stream) {
    const float* returns = (const float*)d_in[0];
    const float* W1      = (const float*)d_in[1];
    const float* b1      = (const float*)d_in[2];
    const float* W2      = (const float*)d_in[3];
    const float* b2      = (const float*)d_in[4];
    const float* W3      = (const float*)d_in[5];
    const float* b3      = (const float*)d_in[6];
    float* out = (float*)d_out;

    const int B = out_size / T_LEN;   // 1024

    dim3 grid(B, 1, 1);               // one block per row; 4 blocks/CU, one round
    dim3 block(BDIM, 1, 1);
    hurst_ldsrow<<<grid, block, 0, stream>>>(returns, W1, b1, W2, b2, W3, b3, out);
}